// Round 5
// baseline (1051.262 us; speedup 1.0000x reference)
//
#include <hip/hip_runtime.h>
#include <hip/hip_bf16.h>

#define B_ 2
#define N_ 4096
#define M_ 12288
#define K_ 64
#define SH_ 32
#define H_ 64
#define GK_ 8
#define NC_ 200

// monotone map float -> uint32 (ascending), and inverse
static __device__ __forceinline__ unsigned f2key(float f) {
  unsigned b = __float_as_uint(f);
  return (b & 0x80000000u) ? ~b : (b | 0x80000000u);
}
static __device__ __forceinline__ float key2f(unsigned u) {
  unsigned b = (u & 0x80000000u) ? (u & 0x7fffffffu) : ~u;
  return __uint_as_float(b);
}

static __device__ __forceinline__ unsigned long long shflxor64(unsigned long long x, int m) {
  unsigned lo = (unsigned)x, hi = (unsigned)(x >> 32);
  lo = (unsigned)__shfl_xor((int)lo, m);
  hi = (unsigned)__shfl_xor((int)hi, m);
  return ((unsigned long long)hi << 32) | lo;
}

// branchless sorted-descending insert into top[0..7]
static __device__ __forceinline__ void ins8(unsigned long long* top, unsigned long long pk) {
  if (pk > top[7]) {
    bool c0=pk>top[0],c1=pk>top[1],c2=pk>top[2],c3=pk>top[3],c4=pk>top[4],c5=pk>top[5],c6=pk>top[6];
    top[7]=c6?top[6]:pk;
    top[6]=c5?top[5]:(c6?pk:top[6]);
    top[5]=c4?top[4]:(c5?pk:top[5]);
    top[4]=c3?top[3]:(c4?pk:top[4]);
    top[3]=c2?top[2]:(c3?pk:top[3]);
    top[2]=c1?top[1]:(c2?pk:top[2]);
    top[1]=c0?top[0]:(c1?pk:top[1]);
    top[0]=c0?pk:top[0];
  }
}

// ---------------- sentinel: encodes which host-side assumption failed ----------------
__global__ __launch_bounds__(256) void sentinel_v5(float* out, int n, float val) {
  int t = blockIdx.x * 256 + threadIdx.x;
  if (t < n) out[t] = val;
}

// ---------------- prep: r_pix (xyz,|r|^2), r_los (xyz,feat), zero gf ----------------
__global__ __launch_bounds__(256) void prep_v5(
    const float* __restrict__ xxx, const float* __restrict__ pix,
    float4* __restrict__ r_pix, float4* __restrict__ r_los, float* __restrict__ gf)
{
  int tid = blockIdx.x * 256 + threadIdx.x;
  if (tid < M_) {
    float th = pix[2*tid], ph = pix[2*tid+1];
    float st = sinf(th);
    float x = st*cosf(ph), y = st*sinf(ph), z = cosf(th);
    r_pix[tid] = make_float4(x, y, z, x*x + y*y + z*z);
  }
  int t2 = tid - M_;
  if (t2 >= 0 && t2 < B_*N_) {
    int b = t2 >> 12, n = t2 & (N_-1);
    const float* xb = xxx + b*3*N_;
    float th = xb[n], ph = xb[N_+n], ft = xb[2*N_+n];
    float st = sinf(th);
    r_los[t2] = make_float4(st*cosf(ph), st*sinf(ph), cosf(th), ft);
  }
  int t3 = tid - M_ - B_*N_;
  if (t3 >= 0 && t3 < B_*H_) gf[t3] = 0.0f;
}

// ---------------- sampler v5: one wave per (b,m) row; no atomics, no barriers ----------------
// Per-lane territory: n == lane (mod 64), 64 values each, keys in LDS.
// Per-lane register top-8; 64 rounds of wave shuffle-argmax with lazy refill.
__global__ __launch_bounds__(128) void sampler_v5(
    const float4* __restrict__ r_pix, const float4* __restrict__ r_los,
    const float* __restrict__ att_w1, const float* __restrict__ att_b1,
    const float* __restrict__ att_w2, const float* __restrict__ att_b2,
    float* __restrict__ pooled)
{
  __shared__ unsigned ukey[2][N_];    // 32 KB; each wave uses its own half
  const int tid  = threadIdx.x;
  const int wv   = tid >> 6;          // wave id = row within block
  const int lane = tid & 63;
  const int b    = blockIdx.y;
  const int m    = blockIdx.x * 2 + wv;

  const float4 p = r_pix[m];
  const float4* rl = r_los + b * N_;
  unsigned* uk = ukey[wv];

  // build keys + initial per-lane top-8. packed = (key<<12) | (4095-n):
  // larger packed == larger cos, then lower index (jax top_k tie rule).
  unsigned long long top[8];
  #pragma unroll
  for (int k = 0; k < 8; ++k) top[k] = 0ull;
  for (int i = 0; i < 64; ++i) {
    int n = lane + 64*i;
    float4 v = rl[n];
    float c = fminf(1.f, fmaxf(-1.f, v.x*p.x + v.y*p.y + v.z*p.z));
    unsigned u = f2key(c);
    uk[n] = u;
    ins8(top, ((unsigned long long)u << 12) | (unsigned)(4095 - n));
  }
  int cnt = 8;

  unsigned selKey = 0; int selN = 0;
  for (int r = 0; r < K_; ++r) {
    if (cnt == 0) {       // refill from own territory (own LDS writes only)
      #pragma unroll
      for (int k = 0; k < 8; ++k) top[k] = 0ull;
      for (int i = 0; i < 64; ++i) {
        int n = lane + 64*i;
        unsigned u = uk[n];
        if (u) ins8(top, ((unsigned long long)u << 12) | (unsigned)(4095 - n));
      }
      cnt = 8;
    }
    unsigned long long best = top[0];
    #pragma unroll
    for (int off = 1; off < 64; off <<= 1) {
      unsigned long long o = shflxor64(best, off);
      best = o > best ? o : best;
    }
    int n = 4095 - (int)(best & 0xFFFull);       // in [0,4095] by construction
    if (lane == r) { selN = n; selKey = (unsigned)(best >> 12); }
    if ((n & 63) == lane) {                      // owner pops its head
      top[0]=top[1]; top[1]=top[2]; top[2]=top[3]; top[3]=top[4];
      top[4]=top[5]; top[5]=top[6]; top[6]=top[7]; top[7]=0ull;
      --cnt;
      uk[n] = 0u;                                // mark consumed
    }
  }

  // attention MLP + softmax + weighted pool: lane r holds winner r
  {
    float v  = key2f(selKey);
    float xg = rl[selN].w;
    float d  = acosf(fminf(1.f, fmaxf(-1.f, v)));
    float acc = att_b2[0];
    for (int s = 0; s < SH_; ++s) {
      float t = xg * att_w1[s] + d * att_w1[SH_ + s] + att_b1[s];
      acc += fmaxf(t, 0.f) * att_w2[s];
    }
    float mx = acc;
    #pragma unroll
    for (int off = 32; off; off >>= 1) mx = fmaxf(mx, __shfl_xor(mx, off));
    float e = expf(acc - mx);
    float se = e, sxe = e * xg;
    #pragma unroll
    for (int off = 32; off; off >>= 1) { se += __shfl_xor(se, off); sxe += __shfl_xor(sxe, off); }
    if (lane == 0) pooled[b*M_ + m] = sxe / se;
  }
}

// ---------------- knn: top-8 by smallest d2 == largest (2*dot - |r_j|^2) ----------------
#define KNN_ROWS 16
#define KNN_TJ 1024

__global__ __launch_bounds__(256) void knn_v5(const float4* __restrict__ r_pix, int* __restrict__ nbr)
{
  __shared__ float4 tile[KNN_TJ];
  const int tid = threadIdx.x;
  const int tl = tid & 15;
  const int i = blockIdx.x * KNN_ROWS + (tid >> 4);
  const float4 pi = r_pix[i];

  float bv[8]; int bidx[8];
  #pragma unroll
  for (int k = 0; k < 8; ++k) { bv[k] = -1e30f; bidx[k] = 0; }

  for (int jt = 0; jt < M_; jt += KNN_TJ) {
    __syncthreads();
    #pragma unroll
    for (int q = 0; q < KNN_TJ/256; ++q) tile[tid + 256*q] = r_pix[jt + tid + 256*q];
    __syncthreads();
    for (int q = 0; q < KNN_TJ/16; ++q) {
      int jj = tl + (q << 4);
      float4 v = tile[jj];
      int j = jt + jj;
      float s = 2.f*(pi.x*v.x + pi.y*v.y + pi.z*v.z) - v.w;
      if (j == i) s = -1e30f;
      if (s > bv[7]) {
        bool c0 = s > bv[0], c1 = s > bv[1], c2 = s > bv[2], c3 = s > bv[3],
             c4 = s > bv[4], c5 = s > bv[5], c6 = s > bv[6];
        bv[7] = c6 ? bv[6] : s;                 bidx[7] = c6 ? bidx[6] : j;
        bv[6] = c5 ? bv[5] : (c6 ? s : bv[6]);  bidx[6] = c5 ? bidx[5] : (c6 ? j : bidx[6]);
        bv[5] = c4 ? bv[4] : (c5 ? s : bv[5]);  bidx[5] = c4 ? bidx[4] : (c5 ? j : bidx[5]);
        bv[4] = c3 ? bv[3] : (c4 ? s : bv[4]);  bidx[4] = c3 ? bidx[3] : (c4 ? j : bidx[4]);
        bv[3] = c2 ? bv[2] : (c3 ? s : bv[3]);  bidx[3] = c2 ? bidx[2] : (c3 ? j : bidx[3]);
        bv[2] = c1 ? bv[1] : (c2 ? s : bv[2]);  bidx[2] = c1 ? bidx[1] : (c2 ? j : bidx[2]);
        bv[1] = c0 ? bv[0] : (c1 ? s : bv[1]);  bidx[1] = c0 ? bidx[0] : (c1 ? j : bidx[1]);
        bv[0] = c0 ? s : bv[0];                 bidx[0] = c0 ? j : bidx[0];
      }
    }
  }
  for (int round = 0; round < GK_; ++round) {
    float v = bv[0]; int id = bidx[0]; int lw = tl;
    #pragma unroll
    for (int mk = 1; mk < 16; mk <<= 1) {
      float ov = __shfl_xor(v, mk, 16);
      int oi = __shfl_xor(id, mk, 16);
      int ol = __shfl_xor(lw, mk, 16);
      if (ov > v || (ov == v && oi < id)) { v = ov; id = oi; lw = ol; }
    }
    if (tl == round) nbr[i*GK_ + round] = id;
    if (tl == lw) {
      bv[0]=bv[1]; bidx[0]=bidx[1]; bv[1]=bv[2]; bidx[1]=bidx[2];
      bv[2]=bv[3]; bidx[2]=bidx[3]; bv[3]=bv[4]; bidx[3]=bidx[4];
      bv[4]=bv[5]; bidx[4]=bidx[5]; bv[5]=bv[6]; bidx[5]=bidx[6];
      bv[6]=bv[7]; bidx[6]=bidx[7]; bv[7]=-1e30f; bidx[7]=0;
    }
  }
}

// ---------------- proj: h0 = relu(pooled * proj_w + proj_b) ----------------
__global__ __launch_bounds__(256) void proj_v5(
    const float* __restrict__ pooled, const float* __restrict__ proj_w,
    const float* __restrict__ proj_b, float* __restrict__ h0)
{
  int t = blockIdx.x * 256 + threadIdx.x;
  int c = t & (H_-1);
  int bm = t >> 6;
  float p = pooled[bm];
  h0[t] = fmaxf(p * proj_w[c] + proj_b[c], 0.f);
}

// ---------------- GNN layer: h' = relu(agg@relW + relB + h@rootW) ----------------
__global__ __launch_bounds__(256) void gnn_v5(
    const float* __restrict__ hin, float* __restrict__ hout, const int* __restrict__ nbr,
    const float* __restrict__ relw, const float* __restrict__ relb,
    const float* __restrict__ rootw)
{
  __shared__ float wrel[H_*H_], wroot[H_*H_], rb[H_];
  const int tid = threadIdx.x;
  #pragma unroll
  for (int q = 0; q < 16; ++q) {
    int idx = tid + 256*q;
    wrel[idx]  = relw[idx];
    wroot[idx] = rootw[idx];
  }
  if (tid < H_) rb[tid] = relb[tid];
  __syncthreads();

  const int lane = tid & 63;
  const int wave = tid >> 6;
  const int b = blockIdx.y;
  const int m0 = blockIdx.x * 16 + wave * 4;
  const float* hb = hin + (size_t)b * M_ * H_;

  float h[4], agg[4], acc[4];
  #pragma unroll
  for (int t = 0; t < 4; ++t) {
    int m = m0 + t;
    h[t] = hb[m*H_ + lane];
    float a = 0.f;
    #pragma unroll
    for (int k = 0; k < GK_; ++k) {
      int nb = nbr[m*GK_ + k];
      nb = nb < 0 ? 0 : (nb >= M_ ? M_-1 : nb);
      a += hb[nb*H_ + lane];
    }
    agg[t] = a;
    acc[t] = rb[lane];
  }
  for (int c = 0; c < H_; ++c) {
    float wr = wrel[c*H_ + lane], wo = wroot[c*H_ + lane];
    #pragma unroll
    for (int t = 0; t < 4; ++t) {
      float a  = __shfl(agg[t], c);
      float hh = __shfl(h[t], c);
      acc[t] += a * wr + hh * wo;
    }
  }
  #pragma unroll
  for (int t = 0; t < 4; ++t)
    hout[((size_t)b*M_ + m0 + t)*H_ + lane] = fmaxf(acc[t], 0.f);
}

// ---------------- reduce: gf[b][c] += sum_m h[b][m][c] ----------------
__global__ __launch_bounds__(256) void reduce_v5(const float* __restrict__ h, float* __restrict__ gf)
{
  const int b = blockIdx.y;
  const int slice = blockIdx.x;
  const int c = threadIdx.x & 63, g = threadIdx.x >> 6;
  const float* hb = h + (size_t)b * M_ * H_;
  const int rows = M_ / 32;
  const int m0 = slice * rows;
  float s = 0.f;
  for (int r = g; r < rows; r += 4) s += hb[(m0 + r)*H_ + c];
  __shared__ float part[256];
  part[threadIdx.x] = s;
  __syncthreads();
  if (g == 0) {
    s = part[c] + part[64 + c] + part[128 + c] + part[192 + c];
    atomicAdd(&gf[b*H_ + c], s);
  }
}

// ---------------- head: out = relu(mean(h)@w1+b1)@w2+b2 ----------------
__global__ __launch_bounds__(256) void head_v5(
    const float* __restrict__ gf, const float* __restrict__ w1,
    const float* __restrict__ b1, const float* __restrict__ w2,
    const float* __restrict__ b2, float* __restrict__ out)
{
  __shared__ float gfm[B_][H_], hid[B_][H_];
  const int tid = threadIdx.x;
  if (tid < B_*H_) gfm[tid >> 6][tid & 63] = gf[tid] * (1.f / (float)M_);
  __syncthreads();
  if (tid < B_*H_) {
    int b = tid >> 6, j = tid & 63;
    float acc = b1[j];
    for (int c = 0; c < H_; ++c) acc += gfm[b][c] * w1[c*H_ + j];
    hid[b][j] = fmaxf(acc, 0.f);
  }
  __syncthreads();
  for (int t = tid; t < B_*NC_; t += 256) {
    int b = t / NC_, o = t - b*NC_;
    float acc = b2[o];
    for (int j = 0; j < H_; ++j) acc += hid[b][j] * w2[j*NC_ + o];
    out[t] = acc;
  }
}

extern "C" void kernel_launch(void* const* d_in, const int* in_sizes, int n_in,
                              void* d_out, int out_size, void* d_ws, size_t ws_size,
                              hipStream_t stream)
{
  float* out = (float*)d_out;

  // ---- assumption checks (discriminating sentinels) ----
  const size_t need = (size_t)M_*16 + (size_t)B_*N_*16 + (size_t)B_*M_*4
                    + (size_t)M_*GK_*4 + 2*(size_t)B_*M_*H_*4 + (size_t)B_*H_*4;
  bool ok_ws = ws_size >= need;
  bool ok_in = (n_in == 15) && (out_size == B_*NC_)
            && in_sizes[0] == B_*3*N_ && in_sizes[1] == M_*2
            && in_sizes[2] == 2*SH_ && in_sizes[5] == 1
            && in_sizes[8] == 3*H_*H_ && in_sizes[13] == H_*NC_;
  if (!ok_ws || !ok_in) {
    sentinel_v5<<<(out_size + 255)/256, 256, 0, stream>>>(out, out_size, ok_in ? 42.f : 43.f);
    return;
  }

  const float* xxx    = (const float*)d_in[0];
  const float* pix    = (const float*)d_in[1];
  const float* att_w1 = (const float*)d_in[2];
  const float* att_b1 = (const float*)d_in[3];
  const float* att_w2 = (const float*)d_in[4];
  const float* att_b2 = (const float*)d_in[5];
  const float* proj_w = (const float*)d_in[6];
  const float* proj_b = (const float*)d_in[7];
  const float* rel_w  = (const float*)d_in[8];
  const float* rel_b  = (const float*)d_in[9];
  const float* root_w = (const float*)d_in[10];
  const float* out_w1 = (const float*)d_in[11];
  const float* out_b1 = (const float*)d_in[12];
  const float* out_w2 = (const float*)d_in[13];
  const float* out_b2 = (const float*)d_in[14];

  char* w = (char*)d_ws;
  float4* r_pix = (float4*)w;  w += (size_t)M_ * 16;
  float4* r_los = (float4*)w;  w += (size_t)B_ * N_ * 16;
  float*  pooled = (float*)w;  w += (size_t)B_ * M_ * 4;
  int*    nbr = (int*)w;       w += (size_t)M_ * GK_ * 4;
  float*  h0 = (float*)w;      w += (size_t)B_ * M_ * H_ * 4;
  float*  h1 = (float*)w;      w += (size_t)B_ * M_ * H_ * 4;
  float*  gf = (float*)w;      w += (size_t)B_ * H_ * 4;

  prep_v5<<<(M_ + B_*N_ + B_*H_ + 255)/256, 256, 0, stream>>>(xxx, pix, r_pix, r_los, gf);
  sampler_v5<<<dim3(M_/2, B_), 128, 0, stream>>>(r_pix, r_los, att_w1, att_b1, att_w2, att_b2, pooled);
  knn_v5<<<M_/KNN_ROWS, 256, 0, stream>>>(r_pix, nbr);
  proj_v5<<<(B_*M_*H_)/256, 256, 0, stream>>>(pooled, proj_w, proj_b, h0);
  gnn_v5<<<dim3(M_/16, B_), 256, 0, stream>>>(h0, h1, nbr, rel_w + 0*H_*H_, rel_b + 0*H_, root_w + 0*H_*H_);
  gnn_v5<<<dim3(M_/16, B_), 256, 0, stream>>>(h1, h0, nbr, rel_w + 1*H_*H_, rel_b + 1*H_, root_w + 1*H_*H_);
  gnn_v5<<<dim3(M_/16, B_), 256, 0, stream>>>(h0, h1, nbr, rel_w + 2*H_*H_, rel_b + 2*H_, root_w + 2*H_*H_);
  reduce_v5<<<dim3(32, B_), 256, 0, stream>>>(h1, gf);
  head_v5<<<1, 256, 0, stream>>>(gf, out_w1, out_b1, out_w2, out_b2, out);
}

// Round 6
// 568.341 us; speedup vs baseline: 1.8497x; 1.8497x over previous
//
#include <hip/hip_runtime.h>
#include <hip/hip_bf16.h>

#define B_ 2
#define N_ 4096
#define M_ 12288
#define K_ 64
#define SH_ 32
#define H_ 64
#define GK_ 8
#define NC_ 200

#define SROWS 8        // rows (waves) per sampler block
#define TILE_ 2048     // float4 elements per tile half
#define CAP_ 96        // boundary-candidate capacity (expected ~16)

// monotone map float -> uint32 (ascending), and inverse
static __device__ __forceinline__ unsigned f2key(float f) {
  unsigned b = __float_as_uint(f);
  return (b & 0x80000000u) ? ~b : (b | 0x80000000u);
}
static __device__ __forceinline__ float key2f(unsigned u) {
  unsigned b = (u & 0x80000000u) ? (u & 0x7fffffffu) : ~u;
  return __uint_as_float(b);
}

// cos + linear bin (uniform in [-1,1] -> ~uniform over 256 bins)
static __device__ __forceinline__ int binOf(const float4 v, const float4 p, float& c) {
  c = fminf(1.f, fmaxf(-1.f, fmaf(v.z, p.z, fmaf(v.y, p.y, v.x * p.x))));
  return min((int)fmaf(c, 128.f, 128.f), 255);
}

// ---------------- sentinel ----------------
__global__ __launch_bounds__(256) void sentinel_v6(float* out, int n, float val) {
  int t = blockIdx.x * 256 + threadIdx.x;
  if (t < n) out[t] = val;
}

// ---------------- prep ----------------
__global__ __launch_bounds__(256) void prep_v6(
    const float* __restrict__ xxx, const float* __restrict__ pix,
    float4* __restrict__ r_pix, float4* __restrict__ r_los, float* __restrict__ gf)
{
  int tid = blockIdx.x * 256 + threadIdx.x;
  if (tid < M_) {
    float th = pix[2*tid], ph = pix[2*tid+1];
    float st = sinf(th);
    float x = st*cosf(ph), y = st*sinf(ph), z = cosf(th);
    r_pix[tid] = make_float4(x, y, z, x*x + y*y + z*z);
  }
  int t2 = tid - M_;
  if (t2 >= 0 && t2 < B_*N_) {
    int b = t2 >> 12, n = t2 & (N_-1);
    const float* xb = xxx + b*3*N_;
    float th = xb[n], ph = xb[N_+n], ft = xb[2*N_+n];
    float st = sinf(th);
    r_los[t2] = make_float4(st*cosf(ph), st*sinf(ph), cosf(th), ft);
  }
  int t3 = tid - M_ - B_*N_;
  if (t3 >= 0 && t3 < B_*H_) gf[t3] = 0.0f;
}

// ---------------- sampler v6: per-wave histogram top-K (exact, jax tie rule) ----------------
// block = 512 threads = 8 waves = 8 rows of same batch; r_los staged in LDS halves.
__global__ __launch_bounds__(512) void sampler_v6(
    const float4* __restrict__ r_pix, const float4* __restrict__ r_los,
    const float* __restrict__ att_w1, const float* __restrict__ att_b1,
    const float* __restrict__ att_w2, const float* __restrict__ att_b2,
    float* __restrict__ pooled)
{
  __shared__ float4 tile[TILE_];                     // 32 KB
  __shared__ unsigned hist[SROWS][256];              // 8 KB
  __shared__ float selC[SROWS][K_];                  // 2 KB
  __shared__ float selX[SROWS][K_];                  // 2 KB
  __shared__ unsigned long long bkey[SROWS][CAP_];   // 6 KB
  __shared__ float bxg[SROWS][CAP_];                 // 3 KB
  __shared__ unsigned cHi[SROWS], cBd[SROWS], s_thr[SROWS];

  const int tid  = threadIdx.x;
  const int wv   = tid >> 6;
  const int lane = tid & 63;
  const int b    = blockIdx.y;
  const int m    = blockIdx.x * SROWS + wv;

  const float4 p = r_pix[m];
  const float4* rl = r_los + b * N_;

  // init
  #pragma unroll
  for (int q = 0; q < 4; ++q) ((unsigned*)hist)[tid + 512*q] = 0u;
  if (tid < SROWS) { cHi[tid] = 0u; cBd[tid] = 0u; }
  selC[wv][lane] = -1.0f;          // safe defaults (never used in normal operation)
  selX[wv][lane] = 0.0f;

  // ---- phase 1: histogram over 256 linear bins (two tile halves) ----
  for (int hh = 0; hh < 2; ++hh) {
    __syncthreads();
    #pragma unroll
    for (int q = 0; q < TILE_/512; ++q)
      tile[tid + 512*q] = rl[hh*TILE_ + tid + 512*q];
    __syncthreads();
    for (int i = 0; i < TILE_/64; ++i) {
      float c;
      int bin = binOf(tile[lane + 64*i], p, c);
      atomicAdd(&hist[wv][bin], 1u);
    }
  }
  __syncthreads();

  // ---- phase 2: per-wave threshold bin via suffix-sum over 256 bins ----
  {
    const int l = lane;
    unsigned h0 = hist[wv][4*l+0], h1 = hist[wv][4*l+1],
             h2 = hist[wv][4*l+2], h3 = hist[wv][4*l+3];
    unsigned g = h0 + h1 + h2 + h3;
    unsigned s = g;                          // -> cnt_ge(4l)
    #pragma unroll
    for (int off = 1; off < 64; off <<= 1) {
      unsigned t = (unsigned)__shfl_down((int)s, off);
      s += (l + off < 64) ? t : 0u;
    }
    unsigned snext = s - g;                  // cnt_ge(4l+4)
    unsigned c3 = h3 + snext, c2 = h2 + c3, c1 = h1 + c2, c0 = h0 + c1;
    unsigned packed = 0u;                    // ((t+1)<<16) | cnt_gt(t)
    if      (c3 >= K_) packed = ((unsigned)(4*l+4) << 16) | snext;
    else if (c2 >= K_) packed = ((unsigned)(4*l+3) << 16) | c3;
    else if (c1 >= K_) packed = ((unsigned)(4*l+2) << 16) | c2;
    else if (c0 >= K_) packed = ((unsigned)(4*l+1) << 16) | c1;
    #pragma unroll
    for (int off = 32; off; off >>= 1) {
      unsigned o = (unsigned)__shfl_xor((int)packed, off);
      packed = packed > o ? packed : o;
    }
    if (l == 0) s_thr[wv] = (packed >> 16) - 1u;   // threshold bin
  }
  __syncthreads();

  // ---- phase 3: collect winners (bin > thr) and boundary candidates (bin == thr) ----
  const int thr = (int)s_thr[wv];
  for (int hh = 0; hh < 2; ++hh) {
    __syncthreads();
    #pragma unroll
    for (int q = 0; q < TILE_/512; ++q)
      tile[tid + 512*q] = rl[hh*TILE_ + tid + 512*q];
    __syncthreads();
    for (int i = 0; i < TILE_/64; ++i) {
      int n0 = lane + 64*i;
      float4 v = tile[n0];
      float c;
      int bin = binOf(v, p, c);
      if (bin > thr) {
        unsigned slot = atomicAdd(&cHi[wv], 1u);
        if (slot < K_) { selC[wv][slot] = c; selX[wv][slot] = v.w; }
      } else if (bin == thr) {
        unsigned q2 = atomicAdd(&cBd[wv], 1u);
        if (q2 < CAP_) {
          int n = hh*TILE_ + n0;
          bkey[wv][q2] = ((unsigned long long)f2key(c) << 12) | (unsigned)(4095 - n);
          bxg[wv][q2]  = v.w;
        }
      }
    }
  }
  __syncthreads();

  // ---- phase 4: boundary resolve — exact rank by (value desc, index asc) ----
  {
    int above = (int)cHi[wv]; if (above > K_) above = K_;
    int need  = K_ - above;
    int cntB  = (int)cBd[wv]; if (cntB > CAP_) cntB = CAP_;
    for (int it = lane; it < cntB; it += 64) {
      unsigned long long mypk = bkey[wv][it];
      int rank = 0;
      for (int j = 0; j < cntB; ++j) rank += (bkey[wv][j] > mypk) ? 1 : 0;
      if (rank < need && above + rank < K_) {
        selC[wv][above + rank] = key2f((unsigned)(mypk >> 12));
        selX[wv][above + rank] = bxg[wv][it];
      }
    }
  }
  __syncthreads();

  // ---- attention MLP + softmax + weighted pool (lane l = winner l) ----
  {
    float c  = selC[wv][lane];
    float xg = selX[wv][lane];
    float d  = acosf(fminf(1.f, fmaxf(-1.f, c)));
    float acc = att_b2[0];
    for (int s = 0; s < SH_; ++s) {
      float t = xg * att_w1[s] + d * att_w1[SH_ + s] + att_b1[s];
      acc += fmaxf(t, 0.f) * att_w2[s];
    }
    float mx = acc;
    #pragma unroll
    for (int off = 32; off; off >>= 1) mx = fmaxf(mx, __shfl_xor(mx, off));
    float e = expf(acc - mx);
    float se = e, sxe = e * xg;
    #pragma unroll
    for (int off = 32; off; off >>= 1) { se += __shfl_xor(se, off); sxe += __shfl_xor(sxe, off); }
    if (lane == 0) pooled[b*M_ + m] = sxe / se;
  }
}

// ---------------- knn: top-8 by smallest d2 == largest (2*dot - |r_j|^2) ----------------
#define KNN_ROWS 16
#define KNN_TJ 1024

__global__ __launch_bounds__(256) void knn_v6(const float4* __restrict__ r_pix, int* __restrict__ nbr)
{
  __shared__ float4 tile[KNN_TJ];
  const int tid = threadIdx.x;
  const int tl = tid & 15;
  const int i = blockIdx.x * KNN_ROWS + (tid >> 4);
  const float4 pi = r_pix[i];

  float bv[8]; int bidx[8];
  #pragma unroll
  for (int k = 0; k < 8; ++k) { bv[k] = -1e30f; bidx[k] = 0; }

  for (int jt = 0; jt < M_; jt += KNN_TJ) {
    __syncthreads();
    #pragma unroll
    for (int q = 0; q < KNN_TJ/256; ++q) tile[tid + 256*q] = r_pix[jt + tid + 256*q];
    __syncthreads();
    for (int q = 0; q < KNN_TJ/16; ++q) {
      int jj = tl + (q << 4);
      float4 v = tile[jj];
      int j = jt + jj;
      float s = 2.f*(pi.x*v.x + pi.y*v.y + pi.z*v.z) - v.w;
      if (j == i) s = -1e30f;
      if (s > bv[7]) {
        bool c0 = s > bv[0], c1 = s > bv[1], c2 = s > bv[2], c3 = s > bv[3],
             c4 = s > bv[4], c5 = s > bv[5], c6 = s > bv[6];
        bv[7] = c6 ? bv[6] : s;                 bidx[7] = c6 ? bidx[6] : j;
        bv[6] = c5 ? bv[5] : (c6 ? s : bv[6]);  bidx[6] = c5 ? bidx[5] : (c6 ? j : bidx[6]);
        bv[5] = c4 ? bv[4] : (c5 ? s : bv[5]);  bidx[5] = c4 ? bidx[4] : (c5 ? j : bidx[5]);
        bv[4] = c3 ? bv[3] : (c4 ? s : bv[4]);  bidx[4] = c3 ? bidx[3] : (c4 ? j : bidx[4]);
        bv[3] = c2 ? bv[2] : (c3 ? s : bv[3]);  bidx[3] = c2 ? bidx[2] : (c3 ? j : bidx[3]);
        bv[2] = c1 ? bv[1] : (c2 ? s : bv[2]);  bidx[2] = c1 ? bidx[1] : (c2 ? j : bidx[2]);
        bv[1] = c0 ? bv[0] : (c1 ? s : bv[1]);  bidx[1] = c0 ? bidx[0] : (c1 ? j : bidx[1]);
        bv[0] = c0 ? s : bv[0];                 bidx[0] = c0 ? j : bidx[0];
      }
    }
  }
  for (int round = 0; round < GK_; ++round) {
    float v = bv[0]; int id = bidx[0]; int lw = tl;
    #pragma unroll
    for (int mk = 1; mk < 16; mk <<= 1) {
      float ov = __shfl_xor(v, mk, 16);
      int oi = __shfl_xor(id, mk, 16);
      int ol = __shfl_xor(lw, mk, 16);
      if (ov > v || (ov == v && oi < id)) { v = ov; id = oi; lw = ol; }
    }
    if (tl == round) nbr[i*GK_ + round] = id;
    if (tl == lw) {
      bv[0]=bv[1]; bidx[0]=bidx[1]; bv[1]=bv[2]; bidx[1]=bidx[2];
      bv[2]=bv[3]; bidx[2]=bidx[3]; bv[3]=bv[4]; bidx[3]=bidx[4];
      bv[4]=bv[5]; bidx[4]=bidx[5]; bv[5]=bv[6]; bidx[5]=bidx[6];
      bv[6]=bv[7]; bidx[6]=bidx[7]; bv[7]=-1e30f; bidx[7]=0;
    }
  }
}

// ---------------- proj ----------------
__global__ __launch_bounds__(256) void proj_v6(
    const float* __restrict__ pooled, const float* __restrict__ proj_w,
    const float* __restrict__ proj_b, float* __restrict__ h0)
{
  int t = blockIdx.x * 256 + threadIdx.x;
  int c = t & (H_-1);
  int bm = t >> 6;
  float p = pooled[bm];
  h0[t] = fmaxf(p * proj_w[c] + proj_b[c], 0.f);
}

// ---------------- GNN layer ----------------
__global__ __launch_bounds__(256) void gnn_v6(
    const float* __restrict__ hin, float* __restrict__ hout, const int* __restrict__ nbr,
    const float* __restrict__ relw, const float* __restrict__ relb,
    const float* __restrict__ rootw)
{
  __shared__ float wrel[H_*H_], wroot[H_*H_], rb[H_];
  const int tid = threadIdx.x;
  #pragma unroll
  for (int q = 0; q < 16; ++q) {
    int idx = tid + 256*q;
    wrel[idx]  = relw[idx];
    wroot[idx] = rootw[idx];
  }
  if (tid < H_) rb[tid] = relb[tid];
  __syncthreads();

  const int lane = tid & 63;
  const int wave = tid >> 6;
  const int b = blockIdx.y;
  const int m0 = blockIdx.x * 16 + wave * 4;
  const float* hb = hin + (size_t)b * M_ * H_;

  float h[4], agg[4], acc[4];
  #pragma unroll
  for (int t = 0; t < 4; ++t) {
    int m = m0 + t;
    h[t] = hb[m*H_ + lane];
    float a = 0.f;
    #pragma unroll
    for (int k = 0; k < GK_; ++k) {
      int nb = nbr[m*GK_ + k];
      nb = nb < 0 ? 0 : (nb >= M_ ? M_-1 : nb);
      a += hb[nb*H_ + lane];
    }
    agg[t] = a;
    acc[t] = rb[lane];
  }
  for (int c = 0; c < H_; ++c) {
    float wr = wrel[c*H_ + lane], wo = wroot[c*H_ + lane];
    #pragma unroll
    for (int t = 0; t < 4; ++t) {
      float a  = __shfl(agg[t], c);
      float hh = __shfl(h[t], c);
      acc[t] += a * wr + hh * wo;
    }
  }
  #pragma unroll
  for (int t = 0; t < 4; ++t)
    hout[((size_t)b*M_ + m0 + t)*H_ + lane] = fmaxf(acc[t], 0.f);
}

// ---------------- reduce ----------------
__global__ __launch_bounds__(256) void reduce_v6(const float* __restrict__ h, float* __restrict__ gf)
{
  const int b = blockIdx.y;
  const int slice = blockIdx.x;
  const int c = threadIdx.x & 63, g = threadIdx.x >> 6;
  const float* hb = h + (size_t)b * M_ * H_;
  const int rows = M_ / 32;
  const int m0 = slice * rows;
  float s = 0.f;
  for (int r = g; r < rows; r += 4) s += hb[(m0 + r)*H_ + c];
  __shared__ float part[256];
  part[threadIdx.x] = s;
  __syncthreads();
  if (g == 0) {
    s = part[c] + part[64 + c] + part[128 + c] + part[192 + c];
    atomicAdd(&gf[b*H_ + c], s);
  }
}

// ---------------- head ----------------
__global__ __launch_bounds__(256) void head_v6(
    const float* __restrict__ gf, const float* __restrict__ w1,
    const float* __restrict__ b1, const float* __restrict__ w2,
    const float* __restrict__ b2, float* __restrict__ out)
{
  __shared__ float gfm[B_][H_], hid[B_][H_];
  const int tid = threadIdx.x;
  if (tid < B_*H_) gfm[tid >> 6][tid & 63] = gf[tid] * (1.f / (float)M_);
  __syncthreads();
  if (tid < B_*H_) {
    int b = tid >> 6, j = tid & 63;
    float acc = b1[j];
    for (int c = 0; c < H_; ++c) acc += gfm[b][c] * w1[c*H_ + j];
    hid[b][j] = fmaxf(acc, 0.f);
  }
  __syncthreads();
  for (int t = tid; t < B_*NC_; t += 256) {
    int b = t / NC_, o = t - b*NC_;
    float acc = b2[o];
    for (int j = 0; j < H_; ++j) acc += hid[b][j] * w2[j*NC_ + o];
    out[t] = acc;
  }
}

extern "C" void kernel_launch(void* const* d_in, const int* in_sizes, int n_in,
                              void* d_out, int out_size, void* d_ws, size_t ws_size,
                              hipStream_t stream)
{
  float* out = (float*)d_out;

  const size_t need = (size_t)M_*16 + (size_t)B_*N_*16 + (size_t)B_*M_*4
                    + (size_t)M_*GK_*4 + 2*(size_t)B_*M_*H_*4 + (size_t)B_*H_*4;
  bool ok_ws = ws_size >= need;
  bool ok_in = (n_in == 15) && (out_size == B_*NC_)
            && in_sizes[0] == B_*3*N_ && in_sizes[1] == M_*2
            && in_sizes[2] == 2*SH_ && in_sizes[5] == 1
            && in_sizes[8] == 3*H_*H_ && in_sizes[13] == H_*NC_;
  if (!ok_ws || !ok_in) {
    sentinel_v6<<<(out_size + 255)/256, 256, 0, stream>>>(out, out_size, ok_in ? 42.f : 43.f);
    return;
  }

  const float* xxx    = (const float*)d_in[0];
  const float* pix    = (const float*)d_in[1];
  const float* att_w1 = (const float*)d_in[2];
  const float* att_b1 = (const float*)d_in[3];
  const float* att_w2 = (const float*)d_in[4];
  const float* att_b2 = (const float*)d_in[5];
  const float* proj_w = (const float*)d_in[6];
  const float* proj_b = (const float*)d_in[7];
  const float* rel_w  = (const float*)d_in[8];
  const float* rel_b  = (const float*)d_in[9];
  const float* root_w = (const float*)d_in[10];
  const float* out_w1 = (const float*)d_in[11];
  const float* out_b1 = (const float*)d_in[12];
  const float* out_w2 = (const float*)d_in[13];
  const float* out_b2 = (const float*)d_in[14];

  char* w = (char*)d_ws;
  float4* r_pix = (float4*)w;  w += (size_t)M_ * 16;
  float4* r_los = (float4*)w;  w += (size_t)B_ * N_ * 16;
  float*  pooled = (float*)w;  w += (size_t)B_ * M_ * 4;
  int*    nbr = (int*)w;       w += (size_t)M_ * GK_ * 4;
  float*  h0 = (float*)w;      w += (size_t)B_ * M_ * H_ * 4;
  float*  h1 = (float*)w;      w += (size_t)B_ * M_ * H_ * 4;
  float*  gf = (float*)w;      w += (size_t)B_ * H_ * 4;

  prep_v6<<<(M_ + B_*N_ + B_*H_ + 255)/256, 256, 0, stream>>>(xxx, pix, r_pix, r_los, gf);
  sampler_v6<<<dim3(M_/SROWS, B_), 512, 0, stream>>>(r_pix, r_los, att_w1, att_b1, att_w2, att_b2, pooled);
  knn_v6<<<M_/KNN_ROWS, 256, 0, stream>>>(r_pix, nbr);
  proj_v6<<<(B_*M_*H_)/256, 256, 0, stream>>>(pooled, proj_w, proj_b, h0);
  gnn_v6<<<dim3(M_/16, B_), 256, 0, stream>>>(h0, h1, nbr, rel_w + 0*H_*H_, rel_b + 0*H_, root_w + 0*H_*H_);
  gnn_v6<<<dim3(M_/16, B_), 256, 0, stream>>>(h1, h0, nbr, rel_w + 1*H_*H_, rel_b + 1*H_, root_w + 1*H_*H_);
  gnn_v6<<<dim3(M_/16, B_), 256, 0, stream>>>(h0, h1, nbr, rel_w + 2*H_*H_, rel_b + 2*H_, root_w + 2*H_*H_);
  reduce_v6<<<dim3(32, B_), 256, 0, stream>>>(h1, gf);
  head_v6<<<1, 256, 0, stream>>>(gf, out_w1, out_b1, out_w2, out_b2, out);
}